// Round 1
// 627.469 us; speedup vs baseline: 1.0007x; 1.0007x over previous
//
#include <hip/hip_runtime.h>
#include <hip/hip_bf16.h>
#include <hip/hip_fp16.h>

#define N_NODES 100000
#define N_EDGES 1600000
#define NF 64
#define EF 32

#define SCAN_B 512
#define SCAN_NB ((N_NODES + SCAN_B - 1) / SCAN_B)  // 196

// edata record (8B): [63:32]=src  [31:0]=ex (full f32 bits)
// ef_s: per-edge 32 x fp16 (64B), written at sorted position p.

__device__ __forceinline__ unsigned pkh2(float a, float b) {
  __half2 h = __floats2half2_rn(a, b);
  return *reinterpret_cast<unsigned*>(&h);
}

// ---------------- K0: tiny prep — v = W_w^T a (160), c = W_b . a, and
// transposed copies of W_msg sub-blocks.
__global__ __launch_bounds__(256) void k0_prep(
    const float* __restrict__ Ww, const float* __restrict__ Wb,
    const float* __restrict__ a, const float* __restrict__ Wmsg,
    float* __restrict__ v, float* __restrict__ W1T, float* __restrict__ W2T,
    float* __restrict__ WmeT) {
  int t = threadIdx.x;
  for (int j = t; j < 160; j += 256) {
    float s = 0.f;
    for (int k = 0; k < 128; ++k) s = fmaf(a[k], Ww[k * 160 + j], s);
    v[j] = s;
  }
  if (t == 0) {
    float s = 0.f;
    for (int k = 0; k < 128; ++k) s = fmaf(a[k], Wb[k], s);
    v[160] = s;  // c
  }
  for (int idx = t; idx < 64 * 64; idx += 256) {
    int j = idx >> 6, i = idx & 63;
    W1T[idx] = Wmsg[i * 160 + j];        // src block, transposed [j][i]
    W2T[idx] = Wmsg[i * 160 + 64 + j];   // dst block
  }
  for (int idx = t; idx < 32 * 64; idx += 256) {
    int j = idx >> 6, i = idx & 63;
    WmeT[idx] = Wmsg[i * 160 + 128 + j]; // edge block
  }
}

// ---------------- K1: per-node precompute — s1, s2 scalars and
// m_src (fp16) = W1 @ nf, m_dst (f32) = W2 @ nf.
__global__ __launch_bounds__(256) void k1_node(
    const float* __restrict__ nf_g, const float* __restrict__ v,
    const float* __restrict__ W1T, const float* __restrict__ W2T,
    float* __restrict__ s1, float* __restrict__ s2,
    __half* __restrict__ m_src_h, float* __restrict__ m_dst) {
  int n = blockIdx.x * 256 + threadIdx.x;
  if (n >= N_NODES) return;
  const float4* nf4 = (const float4*)(nf_g + (size_t)n * NF);
  float acc[64];
#pragma unroll
  for (int i = 0; i < 64; ++i) acc[i] = 0.f;
  float s1a = 0.f, s2a = 0.f;
  for (int j4 = 0; j4 < 16; ++j4) {
    float4 q = nf4[j4];
    float xs[4] = {q.x, q.y, q.z, q.w};
#pragma unroll
    for (int u = 0; u < 4; ++u) {
      int j = j4 * 4 + u;
      float x = xs[u];
      s1a = fmaf(v[j], x, s1a);
      s2a = fmaf(v[64 + j], x, s2a);
      const float* w = W1T + j * 64;
#pragma unroll
      for (int i = 0; i < 64; ++i) acc[i] = fmaf(w[i], x, acc[i]);
    }
  }
  s1[n] = s1a;
  s2[n] = s2a;
  uint4* ms4 = (uint4*)(m_src_h + (size_t)n * NF);
#pragma unroll
  for (int b = 0; b < 8; ++b)
    ms4[b] = make_uint4(pkh2(acc[b * 8 + 0], acc[b * 8 + 1]),
                        pkh2(acc[b * 8 + 2], acc[b * 8 + 3]),
                        pkh2(acc[b * 8 + 4], acc[b * 8 + 5]),
                        pkh2(acc[b * 8 + 6], acc[b * 8 + 7]));
#pragma unroll
  for (int i = 0; i < 64; ++i) acc[i] = 0.f;
  for (int j4 = 0; j4 < 16; ++j4) {
    float4 q = nf4[j4];
    float xs[4] = {q.x, q.y, q.z, q.w};
#pragma unroll
    for (int u = 0; u < 4; ++u) {
      int j = j4 * 4 + u;
      float x = xs[u];
      const float* w = W2T + j * 64;
#pragma unroll
      for (int i = 0; i < 64; ++i) acc[i] = fmaf(w[i], x, acc[i]);
    }
  }
  float* md = m_dst + (size_t)n * NF;
#pragma unroll
  for (int i = 0; i < 64; ++i) md[i] = acc[i];
}

// ---------------- degree count (reads dst only)
__global__ __launch_bounds__(256) void k_count(const int* __restrict__ dst,
                                               int* __restrict__ cnt) {
  int e = blockIdx.x * 256 + threadIdx.x;
  if (e < N_EDGES) atomicAdd(&cnt[dst[e]], 1);
}

// ---------------- hierarchical scan
__global__ __launch_bounds__(SCAN_B) void kS1(const int* __restrict__ cnt,
                                              int* __restrict__ bsum) {
  __shared__ int sh[SCAN_B];
  int t = threadIdx.x;
  int i = blockIdx.x * SCAN_B + t;
  sh[t] = (i < N_NODES) ? cnt[i] : 0;
  __syncthreads();
  for (int d = SCAN_B / 2; d > 0; d >>= 1) {
    if (t < d) sh[t] += sh[t + d];
    __syncthreads();
  }
  if (t == 0) bsum[blockIdx.x] = sh[0];
}

__global__ __launch_bounds__(256) void kS2(const int* __restrict__ bsum,
                                           int* __restrict__ boff,
                                           int* __restrict__ row_ptr) {
  __shared__ int sh[256];
  int t = threadIdx.x;
  sh[t] = (t < SCAN_NB) ? bsum[t] : 0;
  __syncthreads();
  for (int d = 1; d < 256; d <<= 1) {
    int val = (t >= d) ? sh[t - d] : 0;
    __syncthreads();
    sh[t] += val;
    __syncthreads();
  }
  if (t < SCAN_NB) boff[t] = (t == 0) ? 0 : sh[t - 1];
  if (t == 255) row_ptr[N_NODES] = sh[255];
}

__global__ __launch_bounds__(SCAN_B) void kS3(const int* __restrict__ cnt,
                                              const int* __restrict__ boff,
                                              int* __restrict__ row_ptr,
                                              int* __restrict__ cursor) {
  __shared__ int sh[SCAN_B];
  int t = threadIdx.x;
  int i = blockIdx.x * SCAN_B + t;
  int val = (i < N_NODES) ? cnt[i] : 0;
  sh[t] = val;
  __syncthreads();
  for (int d = 1; d < SCAN_B; d <<= 1) {
    int u = (t >= d) ? sh[t - d] : 0;
    __syncthreads();
    sh[t] += u;
    __syncthreads();
  }
  if (i < N_NODES) {
    int excl = boff[blockIdx.x] + sh[t] - val;
    row_ptr[i] = excl;
    cursor[i] = excl;
  }
}

// ---------------- fused: ex = exp(leaky(logit)) + scatter of (src,ex) 8B
// record AND the edge's ef row as 32 x fp16 (64B) at sorted position p.
__global__ __launch_bounds__(256) void kE_scatter(
    const int* __restrict__ src, const int* __restrict__ dst,
    const float* __restrict__ e_feat, const float* __restrict__ s1,
    const float* __restrict__ s2, const float* __restrict__ v,
    int* __restrict__ cursor, unsigned long long* __restrict__ edata,
    __half* __restrict__ ef_s) {
  int e = blockIdx.x * 256 + threadIdx.x;
  if (e >= N_EDGES) return;
  int sn = src[e], dn = dst[e];
  const float4* efr = (const float4*)(e_feat + (size_t)e * EF);
  float4 q[8];
#pragma unroll
  for (int i = 0; i < 8; ++i) q[i] = efr[i];
  float t = 0.f;
#pragma unroll
  for (int i = 0; i < 8; ++i) {
    t = fmaf(q[i].x, v[128 + i * 4 + 0], t);
    t = fmaf(q[i].y, v[128 + i * 4 + 1], t);
    t = fmaf(q[i].z, v[128 + i * 4 + 2], t);
    t = fmaf(q[i].w, v[128 + i * 4 + 3], t);
  }
  float lg = s1[sn] + s2[dn] + t + v[160];
  float l = lg > 0.f ? lg : 0.01f * lg;  // leaky_relu(0.01)
  float ex = __expf(l);
  int p = atomicAdd(&cursor[dn], 1);
  edata[p] = ((unsigned long long)(unsigned)sn << 32) |
             (unsigned long long)__float_as_uint(ex);
  uint4* o4 = (uint4*)(ef_s + (size_t)p * EF);
#pragma unroll
  for (int i = 0; i < 4; ++i)
    o4[i] = make_uint4(pkh2(q[2 * i].x, q[2 * i].y),
                       pkh2(q[2 * i].z, q[2 * i].w),
                       pkh2(q[2 * i + 1].x, q[2 * i + 1].y),
                       pkh2(q[2 * i + 1].z, q[2 * i + 1].w));
}

// ---------------- K3: one wave per dst node. 8B metadata chunk-load;
// groups of 4 edges: 4 fp16 m_src gathers + ONE coalesced half2 ef load
// (lane = (edge-of-4:2 | colpair:4) covers 4 edges x 32 cols in 256B).
__global__ __launch_bounds__(256) void k3_agg(
    const int* __restrict__ row_ptr, const int2* __restrict__ edata,
    const __half* __restrict__ ef_s, const __half* __restrict__ m_src_h,
    const float* __restrict__ m_dst, const float* __restrict__ WmeT,
    const float* __restrict__ Wmsg_b, float* __restrict__ out) {
  int lane = threadIdx.x & 63;
  int wid = threadIdx.x >> 6;
  int n = blockIdx.x * 4 + wid;
  if (n >= N_NODES) return;
  int start = row_ptr[n];
  int end = row_ptr[n + 1];
  int g = lane >> 4;   // which edge of the 4-group this lane's ef load serves
  int c2 = lane & 15;  // column pair
  float sum_ex = 0.f, acc_ms = 0.f;
  float aefx = 0.f, aefy = 0.f;
  for (int base = start; base < end; base += 64) {
    int2 md = make_int2(0, 0);  // pad: src=0, ex=0.0f -> no contribution
    if (base + lane < end) md = edata[base + lane];
    int m = end - base;
    if (m > 64) m = 64;
    int mm4 = (m + 3) & ~3;
    for (int k = 0; k < mm4; k += 4) {
      float ex0 = __uint_as_float((unsigned)__shfl(md.x, k + 0));
      float ex1 = __uint_as_float((unsigned)__shfl(md.x, k + 1));
      float ex2 = __uint_as_float((unsigned)__shfl(md.x, k + 2));
      float ex3 = __uint_as_float((unsigned)__shfl(md.x, k + 3));
      int s0 = __shfl(md.y, k + 0);
      int s1i = __shfl(md.y, k + 1);
      int s2i = __shfl(md.y, k + 2);
      int s3 = __shfl(md.y, k + 3);
      float exg = (g == 0) ? ex0 : (g == 1) ? ex1 : (g == 2) ? ex2 : ex3;
      // coalesced ef load: 4 consecutive sorted edges x 32 cols
      const __half2* ep =
          (const __half2*)(ef_s + ((size_t)(base + k + g)) * EF + c2 * 2);
      float2 ef2 = __half22float2(*ep);
      aefx = fmaf(exg, ef2.x, aefx);
      aefy = fmaf(exg, ef2.y, aefy);
      float ms0 = __half2float(m_src_h[(size_t)s0 * NF + lane]);
      float ms1 = __half2float(m_src_h[(size_t)s1i * NF + lane]);
      float ms2 = __half2float(m_src_h[(size_t)s2i * NF + lane]);
      float ms3 = __half2float(m_src_h[(size_t)s3 * NF + lane]);
      sum_ex += (ex0 + ex1) + (ex2 + ex3);
      acc_ms = fmaf(ex0, ms0, acc_ms);
      acc_ms = fmaf(ex1, ms1, acc_ms);
      acc_ms = fmaf(ex2, ms2, acc_ms);
      acc_ms = fmaf(ex3, ms3, acc_ms);
    }
  }
  // reduce ef accumulators across the 4 lane-groups (same colpair at
  // lanes c2, c2+16, c2+32, c2+48)
  aefx += __shfl_xor(aefx, 16);
  aefx += __shfl_xor(aefx, 32);
  aefy += __shfl_xor(aefy, 16);
  aefy += __shfl_xor(aefy, 32);
  // mm[lane] = sum_j Wme[lane][j] * efc[j]; lane jp holds cols {2jp, 2jp+1}
  float mm = 0.f;
#pragma unroll
  for (int jp = 0; jp < 16; ++jp) {
    float ea = __shfl(aefx, jp);
    float eb = __shfl(aefy, jp);
    mm = fmaf(WmeT[(2 * jp) * 64 + lane], ea, mm);
    mm = fmaf(WmeT[(2 * jp + 1) * 64 + lane], eb, mm);
  }
  float o = 0.f;
  if (sum_ex > 0.f) {
    o = (acc_ms + mm) / sum_ex + m_dst[(size_t)n * NF + lane] + Wmsg_b[lane];
    o = fmaxf(o, 0.f);
  }
  out[(size_t)n * NF + lane] = o;
}

extern "C" void kernel_launch(void* const* d_in, const int* in_sizes, int n_in,
                              void* d_out, int out_size, void* d_ws,
                              size_t ws_size, hipStream_t stream) {
  const float* n_feat = (const float*)d_in[0];
  const float* e_feat = (const float*)d_in[1];
  const int* src = (const int*)d_in[2];
  const int* dst = (const int*)d_in[3];
  const float* Wmsg_w = (const float*)d_in[4];
  const float* Wmsg_b = (const float*)d_in[5];
  const float* W_w = (const float*)d_in[6];
  const float* W_b = (const float*)d_in[7];
  const float* a = (const float*)d_in[8];
  float* out = (float*)d_out;

  char* ws = (char*)d_ws;
  size_t off = 0;
  auto alloc = [&](size_t bytes) -> char* {
    char* p = ws + off;
    off = (off + bytes + 255) & ~(size_t)255;
    return p;
  };
  float* v = (float*)alloc(161 * 4);
  float* W1T = (float*)alloc(64 * 64 * 4);
  float* W2T = (float*)alloc(64 * 64 * 4);
  float* WmeT = (float*)alloc(32 * 64 * 4);
  float* s1 = (float*)alloc(N_NODES * 4);
  float* s2 = (float*)alloc(N_NODES * 4);
  __half* m_src_h = (__half*)alloc((size_t)N_NODES * NF * 2);
  float* m_dst = (float*)alloc((size_t)N_NODES * NF * 4);
  int* cnt = (int*)alloc(N_NODES * 4);
  int* row_ptr = (int*)alloc((N_NODES + 1) * 4);
  int* cursor = (int*)alloc(N_NODES * 4);
  int* bsum = (int*)alloc(SCAN_NB * 4);
  int* boff = (int*)alloc(SCAN_NB * 4);
  unsigned long long* edata = (unsigned long long*)alloc((size_t)N_EDGES * 8);
  __half* ef_s = (__half*)alloc(((size_t)N_EDGES + 8) * EF * 2);
  if (off > ws_size) return;  // workspace too small — fail loudly in check

  k0_prep<<<1, 256, 0, stream>>>(W_w, W_b, a, Wmsg_w, v, W1T, W2T, WmeT);
  k1_node<<<(N_NODES + 255) / 256, 256, 0, stream>>>(n_feat, v, W1T, W2T, s1,
                                                     s2, m_src_h, m_dst);
  hipMemsetAsync(cnt, 0, N_NODES * 4, stream);
  k_count<<<(N_EDGES + 255) / 256, 256, 0, stream>>>(dst, cnt);
  kS1<<<SCAN_NB, SCAN_B, 0, stream>>>(cnt, bsum);
  kS2<<<1, 256, 0, stream>>>(bsum, boff, row_ptr);
  kS3<<<SCAN_NB, SCAN_B, 0, stream>>>(cnt, boff, row_ptr, cursor);
  kE_scatter<<<(N_EDGES + 255) / 256, 256, 0, stream>>>(src, dst, e_feat, s1,
                                                        s2, v, cursor, edata,
                                                        ef_s);
  k3_agg<<<(N_NODES + 3) / 4, 256, 0, stream>>>(row_ptr, (const int2*)edata,
                                                ef_s, m_src_h, m_dst, WmeT,
                                                Wmsg_b, out);
}

// Round 2
// 609.786 us; speedup vs baseline: 1.0297x; 1.0290x over previous
//
#include <hip/hip_runtime.h>
#include <hip/hip_bf16.h>
#include <hip/hip_fp16.h>

#define N_NODES 100000
#define N_EDGES 1600000
#define NF 64
#define EF 32

#define SCAN_B 512
#define SCAN_NB ((N_NODES + SCAN_B - 1) / SCAN_B)  // 196

// ef_s: per-edge sorted record, 64B = 32 x fp16 ef values with src (17 bits)
// bit-stolen: LSB of the 16 low halves = src bits 0..15, bit16 of word 0
// (LSB of ef[1]'s half) = src bit 16. k3 reconstructs src via two ballots
// and recomputes ex = exp(leaky(s1[src]+s2[n]+ef.v+c)) on the fly.

__device__ __forceinline__ unsigned pkh2(float a, float b) {
  __half2 h = __floats2half2_rn(a, b);
  return *reinterpret_cast<unsigned*>(&h);
}

// ---------------- K0: tiny prep — v = W_w^T a (160), c = W_b . a, and
// transposed copies of W_msg sub-blocks.
__global__ __launch_bounds__(256) void k0_prep(
    const float* __restrict__ Ww, const float* __restrict__ Wb,
    const float* __restrict__ a, const float* __restrict__ Wmsg,
    float* __restrict__ v, float* __restrict__ W1T, float* __restrict__ W2T,
    float* __restrict__ WmeT) {
  int t = threadIdx.x;
  for (int j = t; j < 160; j += 256) {
    float s = 0.f;
    for (int k = 0; k < 128; ++k) s = fmaf(a[k], Ww[k * 160 + j], s);
    v[j] = s;
  }
  if (t == 0) {
    float s = 0.f;
    for (int k = 0; k < 128; ++k) s = fmaf(a[k], Wb[k], s);
    v[160] = s;  // c
  }
  for (int idx = t; idx < 64 * 64; idx += 256) {
    int j = idx >> 6, i = idx & 63;
    W1T[idx] = Wmsg[i * 160 + j];        // src block, transposed [j][i]
    W2T[idx] = Wmsg[i * 160 + 64 + j];   // dst block
  }
  for (int idx = t; idx < 32 * 64; idx += 256) {
    int j = idx >> 6, i = idx & 63;
    WmeT[idx] = Wmsg[i * 160 + 128 + j]; // edge block
  }
}

// ---------------- K1: per-node precompute — s1, s2 scalars and
// m_src (fp16) = W1 @ nf, m_dst (f32) = W2 @ nf.
__global__ __launch_bounds__(256) void k1_node(
    const float* __restrict__ nf_g, const float* __restrict__ v,
    const float* __restrict__ W1T, const float* __restrict__ W2T,
    float* __restrict__ s1, float* __restrict__ s2,
    __half* __restrict__ m_src_h, float* __restrict__ m_dst) {
  int n = blockIdx.x * 256 + threadIdx.x;
  if (n >= N_NODES) return;
  const float4* nf4 = (const float4*)(nf_g + (size_t)n * NF);
  float acc[64];
#pragma unroll
  for (int i = 0; i < 64; ++i) acc[i] = 0.f;
  float s1a = 0.f, s2a = 0.f;
  for (int j4 = 0; j4 < 16; ++j4) {
    float4 q = nf4[j4];
    float xs[4] = {q.x, q.y, q.z, q.w};
#pragma unroll
    for (int u = 0; u < 4; ++u) {
      int j = j4 * 4 + u;
      float x = xs[u];
      s1a = fmaf(v[j], x, s1a);
      s2a = fmaf(v[64 + j], x, s2a);
      const float* w = W1T + j * 64;
#pragma unroll
      for (int i = 0; i < 64; ++i) acc[i] = fmaf(w[i], x, acc[i]);
    }
  }
  s1[n] = s1a;
  s2[n] = s2a;
  uint4* ms4 = (uint4*)(m_src_h + (size_t)n * NF);
#pragma unroll
  for (int b = 0; b < 8; ++b)
    ms4[b] = make_uint4(pkh2(acc[b * 8 + 0], acc[b * 8 + 1]),
                        pkh2(acc[b * 8 + 2], acc[b * 8 + 3]),
                        pkh2(acc[b * 8 + 4], acc[b * 8 + 5]),
                        pkh2(acc[b * 8 + 6], acc[b * 8 + 7]));
#pragma unroll
  for (int i = 0; i < 64; ++i) acc[i] = 0.f;
  for (int j4 = 0; j4 < 16; ++j4) {
    float4 q = nf4[j4];
    float xs[4] = {q.x, q.y, q.z, q.w};
#pragma unroll
    for (int u = 0; u < 4; ++u) {
      int j = j4 * 4 + u;
      float x = xs[u];
      const float* w = W2T + j * 64;
#pragma unroll
      for (int i = 0; i < 64; ++i) acc[i] = fmaf(w[i], x, acc[i]);
    }
  }
  float* md = m_dst + (size_t)n * NF;
#pragma unroll
  for (int i = 0; i < 64; ++i) md[i] = acc[i];
}

// ---------------- degree count (reads dst only)
__global__ __launch_bounds__(256) void k_count(const int* __restrict__ dst,
                                               int* __restrict__ cnt) {
  int e = blockIdx.x * 256 + threadIdx.x;
  if (e < N_EDGES) atomicAdd(&cnt[dst[e]], 1);
}

// ---------------- hierarchical scan
__global__ __launch_bounds__(SCAN_B) void kS1(const int* __restrict__ cnt,
                                              int* __restrict__ bsum) {
  __shared__ int sh[SCAN_B];
  int t = threadIdx.x;
  int i = blockIdx.x * SCAN_B + t;
  sh[t] = (i < N_NODES) ? cnt[i] : 0;
  __syncthreads();
  for (int d = SCAN_B / 2; d > 0; d >>= 1) {
    if (t < d) sh[t] += sh[t + d];
    __syncthreads();
  }
  if (t == 0) bsum[blockIdx.x] = sh[0];
}

__global__ __launch_bounds__(256) void kS2(const int* __restrict__ bsum,
                                           int* __restrict__ boff,
                                           int* __restrict__ row_ptr) {
  __shared__ int sh[256];
  int t = threadIdx.x;
  sh[t] = (t < SCAN_NB) ? bsum[t] : 0;
  __syncthreads();
  for (int d = 1; d < 256; d <<= 1) {
    int val = (t >= d) ? sh[t - d] : 0;
    __syncthreads();
    sh[t] += val;
    __syncthreads();
  }
  if (t < SCAN_NB) boff[t] = (t == 0) ? 0 : sh[t - 1];
  if (t == 255) row_ptr[N_NODES] = sh[255];
}

__global__ __launch_bounds__(SCAN_B) void kS3(const int* __restrict__ cnt,
                                              const int* __restrict__ boff,
                                              int* __restrict__ row_ptr,
                                              int* __restrict__ cursor) {
  __shared__ int sh[SCAN_B];
  int t = threadIdx.x;
  int i = blockIdx.x * SCAN_B + t;
  int val = (i < N_NODES) ? cnt[i] : 0;
  sh[t] = val;
  __syncthreads();
  for (int d = 1; d < SCAN_B; d <<= 1) {
    int u = (t >= d) ? sh[t - d] : 0;
    __syncthreads();
    sh[t] += u;
    __syncthreads();
  }
  if (i < N_NODES) {
    int excl = boff[blockIdx.x] + sh[t] - val;
    row_ptr[i] = excl;
    cursor[i] = excl;
  }
}

// ---------------- scatter: pure stream. Read ef row, atomic position,
// pack fp16 record with src bit-stolen, ONE 64B-aligned scattered write.
__global__ __launch_bounds__(256) void kE_scatter(
    const int* __restrict__ src, const int* __restrict__ dst,
    const float* __restrict__ e_feat, int* __restrict__ cursor,
    uint4* __restrict__ ef_s4) {
  int e = blockIdx.x * 256 + threadIdx.x;
  if (e >= N_EDGES) return;
  unsigned sn = (unsigned)src[e];
  int dn = dst[e];
  int p = atomicAdd(&cursor[dn], 1);
  const float4* efr = (const float4*)(e_feat + (size_t)e * EF);
  float4 q[8];
#pragma unroll
  for (int i = 0; i < 8; ++i) q[i] = efr[i];
  unsigned u[16];
#pragma unroll
  for (int i = 0; i < 8; ++i) {
    u[2 * i] = pkh2(q[i].x, q[i].y);
    u[2 * i + 1] = pkh2(q[i].z, q[i].w);
  }
#pragma unroll
  for (int j = 0; j < 16; ++j)
    u[j] = (u[j] & ~1u) | ((sn >> j) & 1u);
  u[0] = (u[0] & ~0x10000u) | (((sn >> 16) & 1u) << 16);
  uint4* o = ef_s4 + (size_t)p * 4;
  o[0] = make_uint4(u[0], u[1], u[2], u[3]);
  o[1] = make_uint4(u[4], u[5], u[6], u[7]);
  o[2] = make_uint4(u[8], u[9], u[10], u[11]);
  o[3] = make_uint4(u[12], u[13], u[14], u[15]);
}

// ---------------- K3: one wave per dst node. Sequential sorted-record
// stream (double-buffered), ballot src-reassembly, on-the-fly ex, fp16
// m_src gathers.
__global__ __launch_bounds__(256) void k3_agg(
    const int* __restrict__ row_ptr, const unsigned* __restrict__ efu,
    const __half* __restrict__ m_src_h, const float* __restrict__ s1,
    const float* __restrict__ s2, const float* __restrict__ v,
    const float* __restrict__ m_dst, const float* __restrict__ WmeT,
    const float* __restrict__ Wmsg_b, float* __restrict__ out) {
  int lane = threadIdx.x & 63;
  int wid = threadIdx.x >> 6;
  int n = blockIdx.x * 4 + wid;
  if (n >= N_NODES) return;
  int start = row_ptr[n];
  int end = row_ptr[n + 1];
  int g = lane >> 4;   // edge-of-4 this lane serves
  int c2 = lane & 15;  // column pair
  float vlo = v[128 + 2 * c2];
  float vhi = v[128 + 2 * c2 + 1];
  float cbias = v[160];
  float s2n = s2[n];
  float sum_ex = 0.f, acc_ms = 0.f;
  float aefx = 0.f, aefy = 0.f;
  // prefetch first record word
  int slot0 = start + g;
  unsigned ucur = efu[(size_t)min(slot0, N_EDGES - 1) * 16 + c2];
  for (int k = start; k < end; k += 4) {
    int slotn = k + 4 + g;
    unsigned unext = efu[(size_t)min(slotn, N_EDGES - 1) * 16 + c2];
    // reassemble the 4 src ids from stolen bits
    unsigned long long b0 = __ballot((int)(ucur & 1u));
    unsigned long long b1 = __ballot((int)(ucur & 0x10000u));
    int s0 = (int)((b0 >> 0) & 0xFFFF) | ((int)((b1 >> 0) & 1) << 16);
    int s1i = (int)((b0 >> 16) & 0xFFFF) | ((int)((b1 >> 16) & 1) << 16);
    int s2i = (int)((b0 >> 32) & 0xFFFF) | ((int)((b1 >> 32) & 1) << 16);
    int s3 = (int)((b0 >> 48) & 0xFFFF) | ((int)((b1 >> 48) & 1) << 16);
    s0 = min(s0, N_NODES - 1);
    s1i = min(s1i, N_NODES - 1);
    s2i = min(s2i, N_NODES - 1);
    s3 = min(s3, N_NODES - 1);
    int sg = (g < 2) ? (g ? s1i : s0) : ((g == 2) ? s2i : s3);
    // issue m_src gathers early (independent of ex)
    float ms0 = __half2float(m_src_h[(size_t)s0 * NF + lane]);
    float ms1 = __half2float(m_src_h[(size_t)s1i * NF + lane]);
    float ms2 = __half2float(m_src_h[(size_t)s2i * NF + lane]);
    float ms3 = __half2float(m_src_h[(size_t)s3 * NF + lane]);
    // ex for own group's edge: t = ef . v (16-lane reduce) + s1 + s2 + c
    __half2 h2 = *reinterpret_cast<__half2*>(&ucur);
    float2 ef2 = __half22float2(h2);
    float pt = fmaf(ef2.y, vhi, ef2.x * vlo);
    pt += __shfl_xor(pt, 1);
    pt += __shfl_xor(pt, 2);
    pt += __shfl_xor(pt, 4);
    pt += __shfl_xor(pt, 8);
    float lg = s1[sg] + s2n + pt + cbias;
    float l = lg > 0.f ? lg : 0.01f * lg;  // leaky_relu(0.01)
    float ex = __expf(l);
    float exv = ((k + g) < end) ? ex : 0.f;  // zero pad slots
    aefx = fmaf(exv, ef2.x, aefx);
    aefy = fmaf(exv, ef2.y, aefy);
    float ex0 = __shfl(exv, 0);
    float ex1 = __shfl(exv, 16);
    float ex2 = __shfl(exv, 32);
    float ex3 = __shfl(exv, 48);
    sum_ex += (ex0 + ex1) + (ex2 + ex3);
    acc_ms = fmaf(ex0, ms0, acc_ms);
    acc_ms = fmaf(ex1, ms1, acc_ms);
    acc_ms = fmaf(ex2, ms2, acc_ms);
    acc_ms = fmaf(ex3, ms3, acc_ms);
    ucur = unext;
  }
  // reduce ef accumulators across the 4 lane-groups
  aefx += __shfl_xor(aefx, 16);
  aefx += __shfl_xor(aefx, 32);
  aefy += __shfl_xor(aefy, 16);
  aefy += __shfl_xor(aefy, 32);
  // mm[lane] = sum_j Wme[lane][j] * aef[j]; lane jp holds cols {2jp,2jp+1}
  float mm = 0.f;
#pragma unroll
  for (int jp = 0; jp < 16; ++jp) {
    float ea = __shfl(aefx, jp);
    float eb = __shfl(aefy, jp);
    mm = fmaf(WmeT[(2 * jp) * 64 + lane], ea, mm);
    mm = fmaf(WmeT[(2 * jp + 1) * 64 + lane], eb, mm);
  }
  float o = 0.f;
  if (sum_ex > 0.f) {
    o = (acc_ms + mm) / sum_ex + m_dst[(size_t)n * NF + lane] + Wmsg_b[lane];
    o = fmaxf(o, 0.f);
  }
  out[(size_t)n * NF + lane] = o;
}

extern "C" void kernel_launch(void* const* d_in, const int* in_sizes, int n_in,
                              void* d_out, int out_size, void* d_ws,
                              size_t ws_size, hipStream_t stream) {
  const float* n_feat = (const float*)d_in[0];
  const float* e_feat = (const float*)d_in[1];
  const int* src = (const int*)d_in[2];
  const int* dst = (const int*)d_in[3];
  const float* Wmsg_w = (const float*)d_in[4];
  const float* Wmsg_b = (const float*)d_in[5];
  const float* W_w = (const float*)d_in[6];
  const float* W_b = (const float*)d_in[7];
  const float* a = (const float*)d_in[8];
  float* out = (float*)d_out;

  char* ws = (char*)d_ws;
  size_t off = 0;
  auto alloc = [&](size_t bytes) -> char* {
    char* p = ws + off;
    off = (off + bytes + 255) & ~(size_t)255;
    return p;
  };
  float* v = (float*)alloc(161 * 4);
  float* W1T = (float*)alloc(64 * 64 * 4);
  float* W2T = (float*)alloc(64 * 64 * 4);
  float* WmeT = (float*)alloc(32 * 64 * 4);
  float* s1 = (float*)alloc(N_NODES * 4);
  float* s2 = (float*)alloc(N_NODES * 4);
  __half* m_src_h = (__half*)alloc((size_t)N_NODES * NF * 2);
  float* m_dst = (float*)alloc((size_t)N_NODES * NF * 4);
  int* cnt = (int*)alloc(N_NODES * 4);
  int* row_ptr = (int*)alloc((N_NODES + 1) * 4);
  int* cursor = (int*)alloc(N_NODES * 4);
  int* bsum = (int*)alloc(SCAN_NB * 4);
  int* boff = (int*)alloc(SCAN_NB * 4);
  __half* ef_s = (__half*)alloc(((size_t)N_EDGES + 8) * EF * 2);
  if (off > ws_size) return;  // workspace too small — fail loudly in check

  k0_prep<<<1, 256, 0, stream>>>(W_w, W_b, a, Wmsg_w, v, W1T, W2T, WmeT);
  k1_node<<<(N_NODES + 255) / 256, 256, 0, stream>>>(n_feat, v, W1T, W2T, s1,
                                                     s2, m_src_h, m_dst);
  hipMemsetAsync(cnt, 0, N_NODES * 4, stream);
  k_count<<<(N_EDGES + 255) / 256, 256, 0, stream>>>(dst, cnt);
  kS1<<<SCAN_NB, SCAN_B, 0, stream>>>(cnt, bsum);
  kS2<<<1, 256, 0, stream>>>(bsum, boff, row_ptr);
  kS3<<<SCAN_NB, SCAN_B, 0, stream>>>(cnt, boff, row_ptr, cursor);
  kE_scatter<<<(N_EDGES + 255) / 256, 256, 0, stream>>>(
      src, dst, e_feat, cursor, (uint4*)ef_s);
  k3_agg<<<(N_NODES + 3) / 4, 256, 0, stream>>>(
      row_ptr, (const unsigned*)ef_s, m_src_h, s1, s2, v, m_dst, WmeT,
      Wmsg_b, out);
}

// Round 3
// 584.776 us; speedup vs baseline: 1.0738x; 1.0428x over previous
//
#include <hip/hip_runtime.h>
#include <hip/hip_bf16.h>
#include <hip/hip_fp16.h>

#define N_NODES 100000
#define N_EDGES 1600000
#define NF 64
#define EF 32

#define SCAN_B 512
#define SCAN_NB ((N_NODES + SCAN_B - 1) / SCAN_B)  // 196
#define CNT_NB ((N_EDGES + 255) / 256)             // 6250
#define K1_NB ((N_NODES + 511) / 512)              // 196

// ef_s: per-edge sorted record, 64B = 32 x fp16 ef values with src (17 bits)
// bit-stolen: LSB of the 16 low halves = src bits 0..15, bit16 of word 0
// (LSB of ef[1]'s half) = src bit 16. k3 reconstructs src via two ballots
// and recomputes ex = exp(leaky(s1[src]+s2[n]+ef.v+c)) on the fly.

__device__ __forceinline__ unsigned pkh2(float a, float b) {
  __half2 h = __floats2half2_rn(a, b);
  return *reinterpret_cast<unsigned*>(&h);
}

// ---------------- kA: fused degree-count+rank (blocks 0..CNT_NB-1) and
// weight prep (last block): v = W_w^T a, c = W_b . a, W_msg transposes.
__global__ __launch_bounds__(256) void kA_count_prep(
    const int* __restrict__ dst, int* __restrict__ cnt, int* __restrict__ rank,
    const float* __restrict__ Ww, const float* __restrict__ Wb,
    const float* __restrict__ a, const float* __restrict__ Wmsg,
    float* __restrict__ v, float* __restrict__ W1T, float* __restrict__ W2T,
    float* __restrict__ WmeT) {
  int b = blockIdx.x;
  int t = threadIdx.x;
  if (b < CNT_NB) {
    int e = b * 256 + t;
    if (e < N_EDGES) rank[e] = atomicAdd(&cnt[dst[e]], 1);
    return;
  }
  // ---- prep block ----
  for (int j = t; j < 160; j += 256) {
    float s = 0.f;
    for (int k = 0; k < 128; ++k) s = fmaf(a[k], Ww[k * 160 + j], s);
    v[j] = s;
  }
  if (t == 0) {
    float s = 0.f;
    for (int k = 0; k < 128; ++k) s = fmaf(a[k], Wb[k], s);
    v[160] = s;  // c
  }
  for (int idx = t; idx < 64 * 64; idx += 256) {
    int j = idx >> 6, i = idx & 63;
    W1T[idx] = Wmsg[i * 160 + j];        // src block, transposed [j][i]
    W2T[idx] = Wmsg[i * 160 + 64 + j];   // dst block
  }
  for (int idx = t; idx < 32 * 64; idx += 256) {
    int j = idx >> 6, i = idx & 63;
    WmeT[idx] = Wmsg[i * 160 + 128 + j]; // edge block
  }
}

// ---------------- kB: fused scan-stage-1 (blocks 0..SCAN_NB-1) and per-node
// precompute k1 (remaining blocks): s1,s2 scalars, m_src fp16, m_dst f32.
__global__ __launch_bounds__(512) void kB_scan1_node(
    const int* __restrict__ cnt, int* __restrict__ bsum,
    const float* __restrict__ nf_g, const float* __restrict__ v,
    const float* __restrict__ W1T, const float* __restrict__ W2T,
    float* __restrict__ s1, float* __restrict__ s2,
    __half* __restrict__ m_src_h, float* __restrict__ m_dst) {
  __shared__ int sh[SCAN_B];
  int t = threadIdx.x;
  if (blockIdx.x < SCAN_NB) {
    int i = blockIdx.x * SCAN_B + t;
    sh[t] = (i < N_NODES) ? cnt[i] : 0;
    __syncthreads();
    for (int d = SCAN_B / 2; d > 0; d >>= 1) {
      if (t < d) sh[t] += sh[t + d];
      __syncthreads();
    }
    if (t == 0) bsum[blockIdx.x] = sh[0];
    return;
  }
  // ---- k1 per-node part ----
  int n = (blockIdx.x - SCAN_NB) * 512 + t;
  if (n >= N_NODES) return;
  const float4* nf4 = (const float4*)(nf_g + (size_t)n * NF);
  float acc[64];
#pragma unroll
  for (int i = 0; i < 64; ++i) acc[i] = 0.f;
  float s1a = 0.f, s2a = 0.f;
  for (int j4 = 0; j4 < 16; ++j4) {
    float4 q = nf4[j4];
    float xs[4] = {q.x, q.y, q.z, q.w};
#pragma unroll
    for (int u = 0; u < 4; ++u) {
      int j = j4 * 4 + u;
      float x = xs[u];
      s1a = fmaf(v[j], x, s1a);
      s2a = fmaf(v[64 + j], x, s2a);
      const float* w = W1T + j * 64;
#pragma unroll
      for (int i = 0; i < 64; ++i) acc[i] = fmaf(w[i], x, acc[i]);
    }
  }
  s1[n] = s1a;
  s2[n] = s2a;
  uint4* ms4 = (uint4*)(m_src_h + (size_t)n * NF);
#pragma unroll
  for (int b = 0; b < 8; ++b)
    ms4[b] = make_uint4(pkh2(acc[b * 8 + 0], acc[b * 8 + 1]),
                        pkh2(acc[b * 8 + 2], acc[b * 8 + 3]),
                        pkh2(acc[b * 8 + 4], acc[b * 8 + 5]),
                        pkh2(acc[b * 8 + 6], acc[b * 8 + 7]));
#pragma unroll
  for (int i = 0; i < 64; ++i) acc[i] = 0.f;
  for (int j4 = 0; j4 < 16; ++j4) {
    float4 q = nf4[j4];
    float xs[4] = {q.x, q.y, q.z, q.w};
#pragma unroll
    for (int u = 0; u < 4; ++u) {
      int j = j4 * 4 + u;
      float x = xs[u];
      const float* w = W2T + j * 64;
#pragma unroll
      for (int i = 0; i < 64; ++i) acc[i] = fmaf(w[i], x, acc[i]);
    }
  }
  float* md = m_dst + (size_t)n * NF;
#pragma unroll
  for (int i = 0; i < 64; ++i) md[i] = acc[i];
}

__global__ __launch_bounds__(256) void kS2(const int* __restrict__ bsum,
                                           int* __restrict__ boff,
                                           int* __restrict__ row_ptr) {
  __shared__ int sh[256];
  int t = threadIdx.x;
  sh[t] = (t < SCAN_NB) ? bsum[t] : 0;
  __syncthreads();
  for (int d = 1; d < 256; d <<= 1) {
    int val = (t >= d) ? sh[t - d] : 0;
    __syncthreads();
    sh[t] += val;
    __syncthreads();
  }
  if (t < SCAN_NB) boff[t] = (t == 0) ? 0 : sh[t - 1];
  if (t == 255) row_ptr[N_NODES] = sh[255];
}

__global__ __launch_bounds__(SCAN_B) void kS3(const int* __restrict__ cnt,
                                              const int* __restrict__ boff,
                                              int* __restrict__ row_ptr) {
  __shared__ int sh[SCAN_B];
  int t = threadIdx.x;
  int i = blockIdx.x * SCAN_B + t;
  int val = (i < N_NODES) ? cnt[i] : 0;
  sh[t] = val;
  __syncthreads();
  for (int d = 1; d < SCAN_B; d <<= 1) {
    int u = (t >= d) ? sh[t - d] : 0;
    __syncthreads();
    sh[t] += u;
    __syncthreads();
  }
  if (i < N_NODES) row_ptr[i] = boff[blockIdx.x] + sh[t] - val;
}

// ---------------- scatter: atomic-free. p = row_ptr[dst] + rank. Read ef
// row, pack fp16 record with src bit-stolen, ONE 64B-aligned write.
__global__ __launch_bounds__(256) void kE_scatter(
    const int* __restrict__ src, const int* __restrict__ dst,
    const int* __restrict__ rank, const int* __restrict__ row_ptr,
    const float* __restrict__ e_feat, uint4* __restrict__ ef_s4) {
  int e = blockIdx.x * 256 + threadIdx.x;
  if (e >= N_EDGES) return;
  unsigned sn = (unsigned)src[e];
  int dn = dst[e];
  int rk = rank[e];
  const float4* efr = (const float4*)(e_feat + (size_t)e * EF);
  float4 q[8];
#pragma unroll
  for (int i = 0; i < 8; ++i) q[i] = efr[i];
  int p = row_ptr[dn] + rk;
  unsigned u[16];
#pragma unroll
  for (int i = 0; i < 8; ++i) {
    u[2 * i] = pkh2(q[i].x, q[i].y);
    u[2 * i + 1] = pkh2(q[i].z, q[i].w);
  }
#pragma unroll
  for (int j = 0; j < 16; ++j)
    u[j] = (u[j] & ~1u) | ((sn >> j) & 1u);
  u[0] = (u[0] & ~0x10000u) | (((sn >> 16) & 1u) << 16);
  uint4* o = ef_s4 + (size_t)p * 4;
  o[0] = make_uint4(u[0], u[1], u[2], u[3]);
  o[1] = make_uint4(u[4], u[5], u[6], u[7]);
  o[2] = make_uint4(u[8], u[9], u[10], u[11]);
  o[3] = make_uint4(u[12], u[13], u[14], u[15]);
}

// ---------------- K3: one wave per dst node. Sequential sorted-record
// stream; 2-stage pipeline: ballots + m_src/s1 gathers issued one 4-edge
// group ahead of consumption.
__global__ __launch_bounds__(256) void k3_agg(
    const int* __restrict__ row_ptr, const unsigned* __restrict__ efu,
    const __half* __restrict__ m_src_h, const float* __restrict__ s1,
    const float* __restrict__ s2, const float* __restrict__ v,
    const float* __restrict__ m_dst, const float* __restrict__ WmeT,
    const float* __restrict__ Wmsg_b, float* __restrict__ out) {
  int lane = threadIdx.x & 63;
  int wid = threadIdx.x >> 6;
  int n = blockIdx.x * 4 + wid;
  if (n >= N_NODES) return;
  int start = row_ptr[n];
  int end = row_ptr[n + 1];
  int g = lane >> 4;   // edge-of-4 this lane serves
  int c2 = lane & 15;  // column pair
  float vlo = v[128 + 2 * c2];
  float vhi = v[128 + 2 * c2 + 1];
  float cbias = v[160];
  float s2n = s2[n];
  float sum_ex = 0.f, acc_ms = 0.f;
  float aefx = 0.f, aefy = 0.f;
  if (start < end) {
    unsigned ucur = efu[(size_t)min(start + g, N_EDGES - 1) * 16 + c2];
    unsigned unxt = efu[(size_t)min(start + 4 + g, N_EDGES - 1) * 16 + c2];
    // stage A: ballots + gathers for group 0
    unsigned long long b0 = __ballot((int)(ucur & 1u));
    unsigned long long b1 = __ballot((int)(ucur & 0x10000u));
    int a0 = min((int)((b0 >> 0) & 0xFFFF) | ((int)((b1 >> 0) & 1) << 16),
                 N_NODES - 1);
    int a1 = min((int)((b0 >> 16) & 0xFFFF) | ((int)((b1 >> 16) & 1) << 16),
                 N_NODES - 1);
    int a2 = min((int)((b0 >> 32) & 0xFFFF) | ((int)((b1 >> 32) & 1) << 16),
                 N_NODES - 1);
    int a3 = min((int)((b0 >> 48) & 0xFFFF) | ((int)((b1 >> 48) & 1) << 16),
                 N_NODES - 1);
    int sgA = (g < 2) ? (g ? a1 : a0) : ((g == 2) ? a2 : a3);
    float s1A = s1[sgA];
    __half hA0 = m_src_h[(size_t)a0 * NF + lane];
    __half hA1 = m_src_h[(size_t)a1 * NF + lane];
    __half hA2 = m_src_h[(size_t)a2 * NF + lane];
    __half hA3 = m_src_h[(size_t)a3 * NF + lane];
    for (int k = start; k < end; k += 4) {
      unsigned ufar = efu[(size_t)min(k + 8 + g, N_EDGES - 1) * 16 + c2];
      // stage B: ballots + issue gathers for group k+4 (consumed next iter)
      unsigned long long c0 = __ballot((int)(unxt & 1u));
      unsigned long long c1 = __ballot((int)(unxt & 0x10000u));
      int e0 = min((int)((c0 >> 0) & 0xFFFF) | ((int)((c1 >> 0) & 1) << 16),
                   N_NODES - 1);
      int e1 = min((int)((c0 >> 16) & 0xFFFF) | ((int)((c1 >> 16) & 1) << 16),
                   N_NODES - 1);
      int e2 = min((int)((c0 >> 32) & 0xFFFF) | ((int)((c1 >> 32) & 1) << 16),
                   N_NODES - 1);
      int e3 = min((int)((c0 >> 48) & 0xFFFF) | ((int)((c1 >> 48) & 1) << 16),
                   N_NODES - 1);
      int sgB = (g < 2) ? (g ? e1 : e0) : ((g == 2) ? e2 : e3);
      float s1B = s1[sgB];
      __half hB0 = m_src_h[(size_t)e0 * NF + lane];
      __half hB1 = m_src_h[(size_t)e1 * NF + lane];
      __half hB2 = m_src_h[(size_t)e2 * NF + lane];
      __half hB3 = m_src_h[(size_t)e3 * NF + lane];
      // ex chain for current group (uses pre-issued s1A; gathers hA* have
      // had a full iteration to land)
      __half2 h2 = *reinterpret_cast<__half2*>(&ucur);
      float2 ef2 = __half22float2(h2);
      float pt = fmaf(ef2.y, vhi, ef2.x * vlo);
      pt += __shfl_xor(pt, 1);
      pt += __shfl_xor(pt, 2);
      pt += __shfl_xor(pt, 4);
      pt += __shfl_xor(pt, 8);
      float lg = s1A + s2n + pt + cbias;
      float l = lg > 0.f ? lg : 0.01f * lg;  // leaky_relu(0.01)
      float exv = ((k + g) < end) ? __expf(l) : 0.f;  // zero pad slots
      aefx = fmaf(exv, ef2.x, aefx);
      aefy = fmaf(exv, ef2.y, aefy);
      float ex0 = __shfl(exv, 0);
      float ex1 = __shfl(exv, 16);
      float ex2 = __shfl(exv, 32);
      float ex3 = __shfl(exv, 48);
      sum_ex += (ex0 + ex1) + (ex2 + ex3);
      acc_ms = fmaf(ex0, __half2float(hA0), acc_ms);
      acc_ms = fmaf(ex1, __half2float(hA1), acc_ms);
      acc_ms = fmaf(ex2, __half2float(hA2), acc_ms);
      acc_ms = fmaf(ex3, __half2float(hA3), acc_ms);
      // rotate pipeline
      ucur = unxt;
      unxt = ufar;
      hA0 = hB0; hA1 = hB1; hA2 = hB2; hA3 = hB3;
      s1A = s1B;
    }
  }
  // reduce ef accumulators across the 4 lane-groups
  aefx += __shfl_xor(aefx, 16);
  aefx += __shfl_xor(aefx, 32);
  aefy += __shfl_xor(aefy, 16);
  aefy += __shfl_xor(aefy, 32);
  // mm[lane] = sum_j Wme[lane][j] * aef[j]; lane jp holds cols {2jp,2jp+1}
  float mm = 0.f;
#pragma unroll
  for (int jp = 0; jp < 16; ++jp) {
    float ea = __shfl(aefx, jp);
    float eb = __shfl(aefy, jp);
    mm = fmaf(WmeT[(2 * jp) * 64 + lane], ea, mm);
    mm = fmaf(WmeT[(2 * jp + 1) * 64 + lane], eb, mm);
  }
  float o = 0.f;
  if (sum_ex > 0.f) {
    o = (acc_ms + mm) / sum_ex + m_dst[(size_t)n * NF + lane] + Wmsg_b[lane];
    o = fmaxf(o, 0.f);
  }
  out[(size_t)n * NF + lane] = o;
}

extern "C" void kernel_launch(void* const* d_in, const int* in_sizes, int n_in,
                              void* d_out, int out_size, void* d_ws,
                              size_t ws_size, hipStream_t stream) {
  const float* n_feat = (const float*)d_in[0];
  const float* e_feat = (const float*)d_in[1];
  const int* src = (const int*)d_in[2];
  const int* dst = (const int*)d_in[3];
  const float* Wmsg_w = (const float*)d_in[4];
  const float* Wmsg_b = (const float*)d_in[5];
  const float* W_w = (const float*)d_in[6];
  const float* W_b = (const float*)d_in[7];
  const float* a = (const float*)d_in[8];
  float* out = (float*)d_out;

  char* ws = (char*)d_ws;
  size_t off = 0;
  auto alloc = [&](size_t bytes) -> char* {
    char* p = ws + off;
    off = (off + bytes + 255) & ~(size_t)255;
    return p;
  };
  float* v = (float*)alloc(161 * 4);
  float* W1T = (float*)alloc(64 * 64 * 4);
  float* W2T = (float*)alloc(64 * 64 * 4);
  float* WmeT = (float*)alloc(32 * 64 * 4);
  float* s1 = (float*)alloc(N_NODES * 4);
  float* s2 = (float*)alloc(N_NODES * 4);
  __half* m_src_h = (__half*)alloc((size_t)N_NODES * NF * 2);
  float* m_dst = (float*)alloc((size_t)N_NODES * NF * 4);
  int* cnt = (int*)alloc(N_NODES * 4);
  int* row_ptr = (int*)alloc((N_NODES + 1) * 4);
  int* rank = (int*)alloc((size_t)N_EDGES * 4);
  int* bsum = (int*)alloc(SCAN_NB * 4);
  int* boff = (int*)alloc(SCAN_NB * 4);
  __half* ef_s = (__half*)alloc(((size_t)N_EDGES + 8) * EF * 2);
  if (off > ws_size) return;  // workspace too small — fail loudly in check

  hipMemsetAsync(cnt, 0, N_NODES * 4, stream);
  kA_count_prep<<<CNT_NB + 1, 256, 0, stream>>>(dst, cnt, rank, W_w, W_b, a,
                                                Wmsg_w, v, W1T, W2T, WmeT);
  kB_scan1_node<<<SCAN_NB + K1_NB, 512, 0, stream>>>(
      cnt, bsum, n_feat, v, W1T, W2T, s1, s2, m_src_h, m_dst);
  kS2<<<1, 256, 0, stream>>>(bsum, boff, row_ptr);
  kS3<<<SCAN_NB, SCAN_B, 0, stream>>>(cnt, boff, row_ptr);
  kE_scatter<<<(N_EDGES + 255) / 256, 256, 0, stream>>>(
      src, dst, rank, row_ptr, e_feat, (uint4*)ef_s);
  k3_agg<<<(N_NODES + 3) / 4, 256, 0, stream>>>(
      row_ptr, (const unsigned*)ef_s, m_src_h, s1, s2, v, m_dst, WmeT,
      Wmsg_b, out);
}